// Round 7
// baseline (205.285 us; speedup 1.0000x reference)
//
#include <hip/hip_runtime.h>

typedef __bf16 bf16x8 __attribute__((ext_vector_type(8)));
typedef __bf16 bf16x4 __attribute__((ext_vector_type(4)));
typedef float f32x4 __attribute__((ext_vector_type(4)));

__device__ __forceinline__ f32x4 mfma16(bf16x8 a, bf16x8 b, f32x4 c) {
  return __builtin_amdgcn_mfma_f32_16x16x32_bf16(a, b, c, 0, 0, 0);
}

__device__ __forceinline__ float fast_exp2(float x) {
  return __builtin_amdgcn_exp2f(x);  // v_exp_f32 (native exp2)
}

typedef const __attribute__((address_space(1))) void gvoid_t;
typedef __attribute__((address_space(3))) void svoid_t;
__device__ __forceinline__ void lds16(const __bf16* g, __bf16* l) {
  // async 16B/lane global->LDS; dest = wave-uniform base + lane*16
  __builtin_amdgcn_global_load_lds((gvoid_t*)g, (svoid_t*)l, 16, 0, 0);
}

// ---------------- fused fp32 -> bf16 convert of all inputs ----------------
__global__ __launch_bounds__(256) void prep(const float* __restrict__ hidden,
                                            const float* __restrict__ Wq,
                                            const float* __restrict__ Wk,
                                            const float* __restrict__ Wv,
                                            const float* __restrict__ Wo,
                                            __bf16* __restrict__ hb,
                                            __bf16* __restrict__ Wqkvb,
                                            __bf16* __restrict__ Wob) {
  int q = blockIdx.x * 256 + threadIdx.x;
  const float* src;
  __bf16* dst;
  if (q < 1048576) {
    src = hidden; dst = hb;
  } else if ((q -= 1048576) < 262144) {
    src = Wq; dst = Wqkvb;
  } else if ((q -= 262144) < 65536) {
    src = Wk; dst = Wqkvb + 1048576;
  } else if ((q -= 65536) < 65536) {
    src = Wv; dst = Wqkvb + 1310720;
  } else {
    q -= 65536;
    src = Wo; dst = Wob;
  }
  float4 v = *(const float4*)(src + (size_t)q * 4);
  bf16x4 o = { (__bf16)v.x, (__bf16)v.y, (__bf16)v.z, (__bf16)v.w };
  *(bf16x4*)(dst + (size_t)q * 4) = o;
}

// ------ NT GEMM, 128x128 tile, global_load_lds dbuf ------
// C[M,N] = A[M,1024] * B[N,1024]^T. 4 waves in 2x2, 64x64 quadrant each.
// LDS tile [128][32] unpadded is exactly lane-ordered for lds16 staging:
// lane i of a 16-row stage: row = i>>2, col = (i&3)*8 -> offset 16*i bytes.
template <bool BF16_OUT>
__global__ __launch_bounds__(256) void gemm_nt(const __bf16* __restrict__ A,
                                               const __bf16* __restrict__ B,
                                               void* __restrict__ Cv, int N) {
  __shared__ __bf16 As[2][128][32];
  __shared__ __bf16 Bs[2][128][32];
  const int m0 = blockIdx.x * 128, n0 = blockIdx.y * 128;
  const int tid = threadIdx.x;
  const int wave = tid >> 6, lane = tid & 63, quad = lane >> 4, l16 = lane & 15;
  const int wr = wave >> 1, wc = wave & 1;
  const int srow = 32 * wave;  // wave stages rows srow..srow+31 (2 insts)
  const __bf16* Ag = A + (size_t)(m0 + srow + (lane >> 2)) * 1024 + (lane & 3) * 8;
  const __bf16* Bg = B + (size_t)(n0 + srow + (lane >> 2)) * 1024 + (lane & 3) * 8;
  f32x4 acc[4][4] = {};

  auto stage = [&](int buf, int k0) {
    lds16(Ag + k0, &As[buf][srow][0]);
    lds16(Ag + 16 * 1024 + k0, &As[buf][srow + 16][0]);
    lds16(Bg + k0, &Bs[buf][srow][0]);
    lds16(Bg + 16 * 1024 + k0, &Bs[buf][srow + 16][0]);
  };
  stage(0, 0);
  __syncthreads();  // drains vmcnt before barrier
  int buf = 0;
  for (int k0 = 0; k0 < 1024; k0 += 32) {
    if (k0 + 32 < 1024) stage(buf ^ 1, k0 + 32);
    bf16x8 af[4], bfr[4];
#pragma unroll
    for (int i = 0; i < 4; i++)
      af[i] = *(bf16x8*)&As[buf][64 * wr + 16 * i + l16][quad * 8];
#pragma unroll
    for (int j = 0; j < 4; j++)
      bfr[j] = *(bf16x8*)&Bs[buf][64 * wc + 16 * j + l16][quad * 8];
#pragma unroll
    for (int i = 0; i < 4; i++)
#pragma unroll
      for (int j = 0; j < 4; j++) acc[i][j] = mfma16(af[i], bfr[j], acc[i][j]);
    __syncthreads();
    buf ^= 1;
  }
#pragma unroll
  for (int i = 0; i < 4; i++)
#pragma unroll
    for (int j = 0; j < 4; j++)
#pragma unroll
      for (int r = 0; r < 4; r++) {
        int row = m0 + 64 * wr + 16 * i + quad * 4 + r;
        int col = n0 + 64 * wc + 16 * j + l16;
        if constexpr (BF16_OUT)
          ((__bf16*)Cv)[(size_t)row * N + col] = (__bf16)acc[i][j][r];
        else
          ((float*)Cv)[(size_t)row * N + col] = acc[i][j][r];
      }
}

// --------- fused RoPE (in-place on QKV) + V transpose + mask bias ----------
__global__ __launch_bounds__(256) void ropevt(__bf16* __restrict__ QKV,
                                              __bf16* __restrict__ VT,
                                              const int* __restrict__ amask,
                                              float* __restrict__ maskb) {
  int idx = blockIdx.x * 256 + threadIdx.x;
  if (idx < 2621440) {
    __bf16* base;
    int m, i;
    if (idx < 2097152) {
      m = idx >> 9;
      int h = (idx >> 4) & 31;
      i = idx & 15;
      base = QKV + (size_t)m * 1536 + h * 32;
    } else {
      int j = idx - 2097152;
      m = j >> 7;
      int h = (j >> 4) & 7;
      i = j & 15;
      base = QKV + (size_t)m * 1536 + 1024 + h * 32;
    }
    int s = m & 2047;
    float inv = __expf(-(float)i * 0.5756462732485114f);  // 10000^(-i/16)
    float ang = (float)s * inv;
    float sn, cs;
    __sincosf(ang, &sn, &cs);
    float x0 = (float)base[i];
    float x1 = (float)base[i + 16];
    base[i] = (__bf16)(x0 * cs - x1 * sn);
    base[i + 16] = (__bf16)(x1 * cs + x0 * sn);
  } else {
    int j = idx - 2621440;
    if (j < 4096) maskb[j] = amask[j] ? -16.0f : -1.5e9f;  // static max folded in
    int s4 = j & 511;
    int d = (j >> 9) & 31;
    int hb_ = j >> 14;
    int s = s4 * 4;
    int b_ = hb_ >> 3, hkv_ = hb_ & 7;
    const __bf16* src = QKV + (size_t)(b_ * 2048 + s) * 1536 + 1280 + hkv_ * 32 + d;
    bf16x4 ov = { src[0], src[1536], src[3072], src[4608] };
    *(bf16x4*)&VT[((size_t)hb_ * 32 + d) * 2048 + s] = ov;
  }
}

// -------- Flash attention: barrier-free, per-wave units, reg prefetch -------
// Wave = one 32-q-row strip; handles strips {xw, 63-xw} (uniform ~33 tiles).
// K/V frags read straight from L2 with distance-1 register double-buffer.
// Static-max softmax (exp2-domain); only LDS use is the per-wave P transform.
__global__ __launch_bounds__(256, 2) void attn(const __bf16* __restrict__ QKV,
                                               const __bf16* __restrict__ VT,
                                               const float* __restrict__ maskb,
                                               __bf16* __restrict__ Ob) {
  __shared__ __bf16 Pl[4][2][16][72];
  const int tid = threadIdx.x;
  const int wave = tid >> 6, lane = tid & 63;
  const int quad = lane >> 4, l16 = lane & 15;
  const int b = blockIdx.z, h = blockIdx.y, hkv = h >> 2;
  const int xw = blockIdx.x * 4 + wave;  // 0..31
  const float SC2 = 0.25503472f;  // (1/sqrt(32)) * log2(e)
  const float* mrow = maskb + b * 2048;
  const __bf16* kbase =
      QKV + (size_t)(b * 2048 + l16) * 1536 + 1024 + hkv * 32 + quad * 8;
  const __bf16* vbase = VT + ((size_t)(b * 8 + hkv) * 32 + l16) * 2048 + quad * 8;

  for (int sp = 0; sp < 2; sp++) {
    const int strip = sp ? 63 - xw : xw;
    const int qw = strip * 32;
    const int q_row0 = qw + l16, q_row1 = qw + 16 + l16;
    const __bf16* qbase =
        QKV + (size_t)(b * 2048 + qw + l16) * 1536 + h * 32 + quad * 8;
    bf16x8 qf0 = *(const bf16x8*)qbase;
    bf16x8 qf1 = *(const bf16x8*)(qbase + 16 * 1536);
    const int ntiles = ((qw + 31) >> 6) + 1;

    f32x4 o00 = {}, o01 = {}, o10 = {}, o11 = {};
    float rs0 = 0.f, rs1 = 0.f;

    bf16x8 kA[4], vA[4], kB[4], vB[4];
#pragma unroll
    for (int kt = 0; kt < 4; kt++)
      kA[kt] = *(const bf16x8*)(kbase + (size_t)(16 * kt) * 1536);
    vA[0] = *(const bf16x8*)(vbase);
    vA[1] = *(const bf16x8*)(vbase + 32);
    vA[2] = *(const bf16x8*)(vbase + 16 * 2048);
    vA[3] = *(const bf16x8*)(vbase + 16 * 2048 + 32);

    auto tile = [&](int t, bf16x8 (&kc)[4], bf16x8 (&vc)[4],
                    bf16x8 (&kn)[4], bf16x8 (&vn)[4]) {
      const int kv0 = t * 64;
      if (t + 1 < ntiles) {  // prefetch next tile into the other buffer
        const __bf16* kp = kbase + (size_t)(kv0 + 64) * 1536;
        const __bf16* vp = vbase + kv0 + 64;
#pragma unroll
        for (int kt = 0; kt < 4; kt++)
          kn[kt] = *(const bf16x8*)(kp + (size_t)(16 * kt) * 1536);
        vn[0] = *(const bf16x8*)(vp);
        vn[1] = *(const bf16x8*)(vp + 32);
        vn[2] = *(const bf16x8*)(vp + 16 * 2048);
        vn[3] = *(const bf16x8*)(vp + 16 * 2048 + 32);
      }
      // ---- S^T = K * Q^T ----
      f32x4 s0[4], s1[4];
#pragma unroll
      for (int kt = 0; kt < 4; kt++) {
        f32x4 z = {};
        s0[kt] = mfma16(kc[kt], qf0, z);
        s1[kt] = mfma16(kc[kt], qf1, z);
      }
      // ---- static-max softmax ----
      float p0[4][4], p1[4][4];
      if (kv0 + 63 <= qw) {  // full tile
#pragma unroll
        for (int kt = 0; kt < 4; kt++) {
          const int kb = kv0 + 16 * kt + 4 * quad;
          float4 mb = *(const float4*)(mrow + kb);
#pragma unroll
          for (int r = 0; r < 4; r++) {
            float e0 = fast_exp2(fmaf(s0[kt][r], SC2, (&mb.x)[r]));
            float e1 = fast_exp2(fmaf(s1[kt][r], SC2, (&mb.x)[r]));
            p0[kt][r] = e0;
            p1[kt][r] = e1;
            rs0 += e0;
            rs1 += e1;
          }
        }
      } else {  // diagonal tile
#pragma unroll
        for (int kt = 0; kt < 4; kt++) {
          const int kb = kv0 + 16 * kt + 4 * quad;
          float4 mb = *(const float4*)(mrow + kb);
#pragma unroll
          for (int r = 0; r < 4; r++) {
            const int key = kb + r;
            float e0 = fast_exp2(fmaf(s0[kt][r], SC2, (&mb.x)[r]));
            float e1 = fast_exp2(fmaf(s1[kt][r], SC2, (&mb.x)[r]));
            p0[kt][r] = (key <= q_row0) ? e0 : 0.f;
            p1[kt][r] = (key <= q_row1) ? e1 : 0.f;
            rs0 += p0[kt][r];
            rs1 += p1[kt][r];
          }
        }
      }
      // ---- both q-tiles' P -> LDS -> B-frags, one wait round ----
#pragma unroll
      for (int kt = 0; kt < 4; kt++) {
        bf16x4 pa = { (__bf16)p0[kt][0], (__bf16)p0[kt][1],
                      (__bf16)p0[kt][2], (__bf16)p0[kt][3] };
        bf16x4 pb = { (__bf16)p1[kt][0], (__bf16)p1[kt][1],
                      (__bf16)p1[kt][2], (__bf16)p1[kt][3] };
        *(bf16x4*)&Pl[wave][0][l16][16 * kt + 4 * quad] = pa;
        *(bf16x4*)&Pl[wave][1][l16][16 * kt + 4 * quad] = pb;
      }
      asm volatile("s_waitcnt lgkmcnt(0)" ::: "memory");
      bf16x8 pf00 = *(bf16x8*)&Pl[wave][0][l16][8 * quad];
      bf16x8 pf01 = *(bf16x8*)&Pl[wave][0][l16][32 + 8 * quad];
      bf16x8 pf10 = *(bf16x8*)&Pl[wave][1][l16][8 * quad];
      bf16x8 pf11 = *(bf16x8*)&Pl[wave][1][l16][32 + 8 * quad];
      asm volatile("s_waitcnt lgkmcnt(0)" ::: "memory");
      // ---- O^T += V^T * P^T ----
      o00 = mfma16(vc[0], pf00, o00);
      o00 = mfma16(vc[1], pf01, o00);
      o01 = mfma16(vc[2], pf00, o01);
      o01 = mfma16(vc[3], pf01, o01);
      o10 = mfma16(vc[0], pf10, o10);
      o10 = mfma16(vc[1], pf11, o10);
      o11 = mfma16(vc[2], pf10, o11);
      o11 = mfma16(vc[3], pf11, o11);
    };

    for (int t = 0; t < ntiles; t += 2) {
      tile(t, kA, vA, kB, vB);
      if (t + 1 < ntiles) tile(t + 1, kB, vB, kA, vA);
    }

    // ---- epilogue: reduce row sums across quads, normalize, store ----
    rs0 += __shfl_xor(rs0, 16);
    rs0 += __shfl_xor(rs0, 32);
    rs1 += __shfl_xor(rs1, 16);
    rs1 += __shfl_xor(rs1, 32);
    float inv0 = 1.0f / rs0, inv1 = 1.0f / rs1;
    size_t row0 = (size_t)(b * 2048 + q_row0);
    size_t row1 = (size_t)(b * 2048 + q_row1);
    bf16x4 w00 = { (__bf16)(o00[0] * inv0), (__bf16)(o00[1] * inv0),
                   (__bf16)(o00[2] * inv0), (__bf16)(o00[3] * inv0) };
    bf16x4 w01 = { (__bf16)(o01[0] * inv0), (__bf16)(o01[1] * inv0),
                   (__bf16)(o01[2] * inv0), (__bf16)(o01[3] * inv0) };
    bf16x4 w10 = { (__bf16)(o10[0] * inv1), (__bf16)(o10[1] * inv1),
                   (__bf16)(o10[2] * inv1), (__bf16)(o10[3] * inv1) };
    bf16x4 w11 = { (__bf16)(o11[0] * inv1), (__bf16)(o11[1] * inv1),
                   (__bf16)(o11[2] * inv1), (__bf16)(o11[3] * inv1) };
    *(bf16x4*)&Ob[row0 * 1024 + h * 32 + quad * 4] = w00;
    *(bf16x4*)&Ob[row0 * 1024 + h * 32 + 16 + quad * 4] = w01;
    *(bf16x4*)&Ob[row1 * 1024 + h * 32 + quad * 4] = w10;
    *(bf16x4*)&Ob[row1 * 1024 + h * 32 + 16 + quad * 4] = w11;
  }
}

extern "C" void kernel_launch(void* const* d_in, const int* in_sizes, int n_in,
                              void* d_out, int out_size, void* d_ws, size_t ws_size,
                              hipStream_t stream) {
  const float* hidden = (const float*)d_in[0];
  const int* amask = (const int*)d_in[1];
  const float* Wq = (const float*)d_in[2];
  const float* Wk = (const float*)d_in[3];
  const float* Wv = (const float*)d_in[4];
  const float* Wo = (const float*)d_in[5];
  float* out = (float*)d_out;

  char* p = (char*)d_ws;
  auto carve = [&](size_t elems) {
    __bf16* r = (__bf16*)p;
    p += ((elems * 2 + 255) / 256) * 256;
    return r;
  };
  __bf16* hb = carve(4096ull * 1024);
  __bf16* Wqkvb = carve(1536ull * 1024);
  __bf16* Wob = carve(1024ull * 1024);
  __bf16* QKV = carve(4096ull * 1536);
  __bf16* VT = carve(4096ull * 256);
  __bf16* Ob = carve(4096ull * 1024);
  float* maskb = (float*)carve(8192);  // 4096 floats

  prep<<<6656, 256, 0, stream>>>(hidden, Wq, Wk, Wv, Wo, hb, Wqkvb, Wob);

  gemm_nt<true><<<dim3(32, 12), 256, 0, stream>>>(hb, Wqkvb, QKV, 1536);

  ropevt<<<11264, 256, 0, stream>>>(QKV, VT, amask, maskb);

  attn<<<dim3(8, 32, 2), 256, 0, stream>>>(QKV, VT, maskb, Ob);

  gemm_nt<false><<<dim3(32, 8), 256, 0, stream>>>(Ob, Wob, (void*)out, 1024);
}

// Round 8
// 199.717 us; speedup vs baseline: 1.0279x; 1.0279x over previous
//
#include <hip/hip_runtime.h>

typedef __bf16 bf16x8 __attribute__((ext_vector_type(8)));
typedef __bf16 bf16x4 __attribute__((ext_vector_type(4)));
typedef short short4v __attribute__((ext_vector_type(4)));
typedef float f32x4 __attribute__((ext_vector_type(4)));

__device__ __forceinline__ f32x4 mfma16(bf16x8 a, bf16x8 b, f32x4 c) {
  return __builtin_amdgcn_mfma_f32_16x16x32_bf16(a, b, c, 0, 0, 0);
}

// K=16 MFMA: C/D layout == B-operand layout -> S^T frags feed PV directly.
__device__ __forceinline__ f32x4 mfma16k16(bf16x4 a, bf16x4 b, f32x4 c) {
#if __has_builtin(__builtin_amdgcn_mfma_f32_16x16x16bf16_1k)
  short4v as = __builtin_bit_cast(short4v, a);
  short4v bs = __builtin_bit_cast(short4v, b);
  return __builtin_amdgcn_mfma_f32_16x16x16bf16_1k(as, bs, c, 0, 0, 0);
#else
  f32x4 d;
  asm volatile("v_mfma_f32_16x16x16_bf16 %0, %1, %2, %3"
               : "=v"(d)
               : "v"(a), "v"(b), "v"(c));
  return d;
#endif
}

__device__ __forceinline__ float fast_exp2(float x) {
  return __builtin_amdgcn_exp2f(x);  // v_exp_f32 (native exp2)
}

typedef const __attribute__((address_space(1))) void gvoid_t;
typedef __attribute__((address_space(3))) void svoid_t;
__device__ __forceinline__ void lds16(const __bf16* g, __bf16* l) {
  // async 16B/lane global->LDS; dest = wave-uniform base + lane*16
  __builtin_amdgcn_global_load_lds((gvoid_t*)g, (svoid_t*)l, 16, 0, 0);
}

// ---------------- fused fp32 -> bf16 convert of all inputs ----------------
__global__ __launch_bounds__(256) void prep(const float* __restrict__ hidden,
                                            const float* __restrict__ Wq,
                                            const float* __restrict__ Wk,
                                            const float* __restrict__ Wv,
                                            const float* __restrict__ Wo,
                                            __bf16* __restrict__ hb,
                                            __bf16* __restrict__ Wqkvb,
                                            __bf16* __restrict__ Wob) {
  int q = blockIdx.x * 256 + threadIdx.x;
  const float* src;
  __bf16* dst;
  if (q < 1048576) {
    src = hidden; dst = hb;
  } else if ((q -= 1048576) < 262144) {
    src = Wq; dst = Wqkvb;
  } else if ((q -= 262144) < 65536) {
    src = Wk; dst = Wqkvb + 1048576;
  } else if ((q -= 65536) < 65536) {
    src = Wv; dst = Wqkvb + 1310720;
  } else {
    q -= 65536;
    src = Wo; dst = Wob;
  }
  float4 v = *(const float4*)(src + (size_t)q * 4);
  bf16x4 o = { (__bf16)v.x, (__bf16)v.y, (__bf16)v.z, (__bf16)v.w };
  *(bf16x4*)(dst + (size_t)q * 4) = o;
}

// ------ NT GEMM, 128x64 tile, global_load_lds dbuf ------
// C[M,N] = A[M,1024]*B[N,1024]^T. 4 waves in 2x2; wave = 64x32 quadrant.
// Unpadded [rows][32] LDS is exactly lane-ordered for lds16 staging.
template <bool BF16_OUT>
__global__ __launch_bounds__(256) void gemm_nt(const __bf16* __restrict__ A,
                                               const __bf16* __restrict__ B,
                                               void* __restrict__ Cv, int N) {
  __shared__ __bf16 As[2][128][32];
  __shared__ __bf16 Bs[2][64][32];
  const int m0 = blockIdx.x * 128, n0 = blockIdx.y * 64;
  const int tid = threadIdx.x;
  const int wave = tid >> 6, lane = tid & 63, quad = lane >> 4, l16 = lane & 15;
  const int wr = wave >> 1, wc = wave & 1;
  const int srA = 32 * wave, srB = 16 * wave;
  const __bf16* Ag = A + (size_t)(m0 + srA + (lane >> 2)) * 1024 + (lane & 3) * 8;
  const __bf16* Bg = B + (size_t)(n0 + srB + (lane >> 2)) * 1024 + (lane & 3) * 8;
  f32x4 acc[4][2] = {};

  auto stage = [&](int buf, int k0) {
    lds16(Ag + k0, &As[buf][srA][0]);
    lds16(Ag + 16 * 1024 + k0, &As[buf][srA + 16][0]);
    lds16(Bg + k0, &Bs[buf][srB][0]);
  };
  stage(0, 0);
  __syncthreads();
  int buf = 0;
  for (int k0 = 0; k0 < 1024; k0 += 32) {
    if (k0 + 32 < 1024) stage(buf ^ 1, k0 + 32);
    bf16x8 af[4], bfr[2];
#pragma unroll
    for (int i = 0; i < 4; i++)
      af[i] = *(bf16x8*)&As[buf][64 * wr + 16 * i + l16][quad * 8];
#pragma unroll
    for (int j = 0; j < 2; j++)
      bfr[j] = *(bf16x8*)&Bs[buf][32 * wc + 16 * j + l16][quad * 8];
#pragma unroll
    for (int i = 0; i < 4; i++)
#pragma unroll
      for (int j = 0; j < 2; j++) acc[i][j] = mfma16(af[i], bfr[j], acc[i][j]);
    __syncthreads();
    buf ^= 1;
  }
#pragma unroll
  for (int i = 0; i < 4; i++)
#pragma unroll
    for (int j = 0; j < 2; j++)
#pragma unroll
      for (int r = 0; r < 4; r++) {
        int row = m0 + 64 * wr + 16 * i + quad * 4 + r;
        int col = n0 + 32 * wc + 16 * j + l16;
        if constexpr (BF16_OUT)
          ((__bf16*)Cv)[(size_t)row * N + col] = (__bf16)acc[i][j][r];
        else
          ((float*)Cv)[(size_t)row * N + col] = acc[i][j][r];
      }
}

// --------- fused RoPE (in-place on QKV) + V transpose + mask bias ----------
__global__ __launch_bounds__(256) void ropevt(__bf16* __restrict__ QKV,
                                              __bf16* __restrict__ VT,
                                              const int* __restrict__ amask,
                                              float* __restrict__ maskb) {
  int idx = blockIdx.x * 256 + threadIdx.x;
  if (idx < 2621440) {
    __bf16* base;
    int m, i;
    if (idx < 2097152) {
      m = idx >> 9;
      int h = (idx >> 4) & 31;
      i = idx & 15;
      base = QKV + (size_t)m * 1536 + h * 32;
    } else {
      int j = idx - 2097152;
      m = j >> 7;
      int h = (j >> 4) & 7;
      i = j & 15;
      base = QKV + (size_t)m * 1536 + 1024 + h * 32;
    }
    int s = m & 2047;
    float inv = __expf(-(float)i * 0.5756462732485114f);  // 10000^(-i/16)
    float ang = (float)s * inv;
    float sn, cs;
    __sincosf(ang, &sn, &cs);
    float x0 = (float)base[i];
    float x1 = (float)base[i + 16];
    base[i] = (__bf16)(x0 * cs - x1 * sn);
    base[i + 16] = (__bf16)(x1 * cs + x0 * sn);
  } else {
    int j = idx - 2621440;
    if (j < 4096) maskb[j] = amask[j] ? -16.0f : -1.5e9f;  // static max folded in
    int s4 = j & 511;
    int d = (j >> 9) & 31;
    int hb_ = j >> 14;
    int s = s4 * 4;
    int b_ = hb_ >> 3, hkv_ = hb_ & 7;
    const __bf16* src = QKV + (size_t)(b_ * 2048 + s) * 1536 + 1280 + hkv_ * 32 + d;
    bf16x4 ov = { src[0], src[1536], src[3072], src[4608] };
    *(bf16x4*)&VT[((size_t)hb_ * 32 + d) * 2048 + s] = ov;
  }
}

// ---------------- Flash attention: register-P, K=16 PV, LDS-staged K/V ------
// Block = 128 q rows of one (b,h), paired strips {xp,15-xp} (uniform work).
// S^T = K*Q^T (16x16x32); softmax output packs directly into the B-operand
// of mfma_16x16x16 for PV (C/D layout == B layout) -> no P LDS round-trip.
__global__ __launch_bounds__(256, 2) void attn(const __bf16* __restrict__ QKV,
                                               const __bf16* __restrict__ VT,
                                               const float* __restrict__ maskb,
                                               __bf16* __restrict__ Ob) {
  __shared__ __bf16 Ks[2][64][40];
  __shared__ __bf16 Vs[2][32][72];
  const int tid = threadIdx.x;
  const int wave = tid >> 6, lane = tid & 63;
  const int quad = lane >> 4, l16 = lane & 15;
  const int b = blockIdx.z, h = blockIdx.y, hkv = h >> 2;
  const int xp = blockIdx.x;  // 0..7
  const float SC2 = 0.25503472f;  // (1/sqrt(32)) * log2(e)

  const int sk_key = tid >> 2, sk_ch = (tid & 3) * 8;
  const int sv_d = tid >> 3, sv_seg = (tid & 7) * 8;
  const __bf16* ksrc = QKV + (size_t)(b * 2048 + sk_key) * 1536 + 1024 + hkv * 32 + sk_ch;
  const __bf16* vsrc = VT + ((size_t)(b * 8 + hkv) * 32 + sv_d) * 2048 + sv_seg;
  const float* mrow = maskb + b * 2048;

  for (int sp = 0; sp < 2; sp++) {
    const int strip = sp ? 15 - xp : xp;
    const int qw = strip * 128 + wave * 32;
    const int q_row0 = qw + l16, q_row1 = qw + 16 + l16;
    const __bf16* qbase = QKV + (size_t)(b * 2048 + qw + l16) * 1536 + h * 32 + quad * 8;
    bf16x8 qf0 = *(const bf16x8*)qbase;
    bf16x8 qf1 = *(const bf16x8*)(qbase + 16 * 1536);

    {  // stage tile 0 into buffer 0
      uint4 kr = *(const uint4*)ksrc;
      uint4 vr = *(const uint4*)vsrc;
      *(uint4*)&Ks[0][sk_key][sk_ch] = kr;
      *(uint4*)&Vs[0][sv_d][sv_seg] = vr;
    }
    __syncthreads();

    f32x4 o00 = {}, o01 = {}, o10 = {}, o11 = {};
    float rs0 = 0.f, rs1 = 0.f;
    int buf = 0;
    const int ntiles = 2 * strip + 2;

    for (int t = 0; t < ntiles; t++) {
      const int kv0 = t << 6;
      const bool more = (t + 1 < ntiles);
      uint4 kr, vr;
      if (more) {
        kr = *(const uint4*)(ksrc + (size_t)(t + 1) * 64 * 1536);
        vr = *(const uint4*)(vsrc + (size_t)(t + 1) * 64);
      }
      if (kv0 <= qw + 31) {  // wave-uniform: any visible key?
        bf16x8 kf[4];
#pragma unroll
        for (int kt = 0; kt < 4; kt++)
          kf[kt] = *(bf16x8*)&Ks[buf][16 * kt + l16][quad * 8];
        f32x4 s0[4], s1[4];
#pragma unroll
        for (int kt = 0; kt < 4; kt++) {
          f32x4 z = {};
          s0[kt] = mfma16(kf[kt], qf0, z);
          s1[kt] = mfma16(kf[kt], qf1, z);
        }
        // ---- static-max softmax -> packed B-operands (registers only) ----
        bf16x4 pb0[4], pb1[4];
        if (kv0 + 63 <= qw) {  // full tile
#pragma unroll
          for (int kt = 0; kt < 4; kt++) {
            const int kb = kv0 + 16 * kt + 4 * quad;
            float4 mb = *(const float4*)(mrow + kb);
#pragma unroll
            for (int r = 0; r < 4; r++) {
              float e0 = fast_exp2(fmaf(s0[kt][r], SC2, (&mb.x)[r]));
              float e1 = fast_exp2(fmaf(s1[kt][r], SC2, (&mb.x)[r]));
              rs0 += e0;
              rs1 += e1;
              pb0[kt][r] = (__bf16)e0;
              pb1[kt][r] = (__bf16)e1;
            }
          }
        } else {  // diagonal tile
#pragma unroll
          for (int kt = 0; kt < 4; kt++) {
            const int kb = kv0 + 16 * kt + 4 * quad;
            float4 mb = *(const float4*)(mrow + kb);
#pragma unroll
            for (int r = 0; r < 4; r++) {
              const int key = kb + r;
              float e0 = fast_exp2(fmaf(s0[kt][r], SC2, (&mb.x)[r]));
              float e1 = fast_exp2(fmaf(s1[kt][r], SC2, (&mb.x)[r]));
              e0 = (key <= q_row0) ? e0 : 0.f;
              e1 = (key <= q_row1) ? e1 : 0.f;
              rs0 += e0;
              rs1 += e1;
              pb0[kt][r] = (__bf16)e0;
              pb1[kt][r] = (__bf16)e1;
            }
          }
        }
        // ---- PV via K=16 MFMA: A = V^T frags (8B LDS reads), B = pb regs ---
#pragma unroll
        for (int kt = 0; kt < 4; kt++) {
          bf16x4 v0 = *(bf16x4*)&Vs[buf][l16][16 * kt + 4 * quad];
          bf16x4 v1 = *(bf16x4*)&Vs[buf][16 + l16][16 * kt + 4 * quad];
          o00 = mfma16k16(v0, pb0[kt], o00);
          o01 = mfma16k16(v1, pb0[kt], o01);
          o10 = mfma16k16(v0, pb1[kt], o10);
          o11 = mfma16k16(v1, pb1[kt], o11);
        }
      }
      if (more) {
        *(uint4*)&Ks[buf ^ 1][sk_key][sk_ch] = kr;
        *(uint4*)&Vs[buf ^ 1][sv_d][sv_seg] = vr;
      }
      __syncthreads();
      buf ^= 1;
    }
    // ---- epilogue ----
    rs0 += __shfl_xor(rs0, 16);
    rs0 += __shfl_xor(rs0, 32);
    rs1 += __shfl_xor(rs1, 16);
    rs1 += __shfl_xor(rs1, 32);
    float inv0 = 1.0f / rs0, inv1 = 1.0f / rs1;
    size_t row0 = (size_t)(b * 2048 + q_row0);
    size_t row1 = (size_t)(b * 2048 + q_row1);
    bf16x4 w00 = { (__bf16)(o00[0] * inv0), (__bf16)(o00[1] * inv0),
                   (__bf16)(o00[2] * inv0), (__bf16)(o00[3] * inv0) };
    bf16x4 w01 = { (__bf16)(o01[0] * inv0), (__bf16)(o01[1] * inv0),
                   (__bf16)(o01[2] * inv0), (__bf16)(o01[3] * inv0) };
    bf16x4 w10 = { (__bf16)(o10[0] * inv1), (__bf16)(o10[1] * inv1),
                   (__bf16)(o10[2] * inv1), (__bf16)(o10[3] * inv1) };
    bf16x4 w11 = { (__bf16)(o11[0] * inv1), (__bf16)(o11[1] * inv1),
                   (__bf16)(o11[2] * inv1), (__bf16)(o11[3] * inv1) };
    *(bf16x4*)&Ob[row0 * 1024 + h * 32 + quad * 4] = w00;
    *(bf16x4*)&Ob[row0 * 1024 + h * 32 + 16 + quad * 4] = w01;
    *(bf16x4*)&Ob[row1 * 1024 + h * 32 + quad * 4] = w10;
    *(bf16x4*)&Ob[row1 * 1024 + h * 32 + 16 + quad * 4] = w11;
  }
}

extern "C" void kernel_launch(void* const* d_in, const int* in_sizes, int n_in,
                              void* d_out, int out_size, void* d_ws, size_t ws_size,
                              hipStream_t stream) {
  const float* hidden = (const float*)d_in[0];
  const int* amask = (const int*)d_in[1];
  const float* Wq = (const float*)d_in[2];
  const float* Wk = (const float*)d_in[3];
  const float* Wv = (const float*)d_in[4];
  const float* Wo = (const float*)d_in[5];
  float* out = (float*)d_out;

  char* p = (char*)d_ws;
  auto carve = [&](size_t elems) {
    __bf16* r = (__bf16*)p;
    p += ((elems * 2 + 255) / 256) * 256;
    return r;
  };
  __bf16* hb = carve(4096ull * 1024);
  __bf16* Wqkvb = carve(1536ull * 1024);
  __bf16* Wob = carve(1024ull * 1024);
  __bf16* QKV = carve(4096ull * 1536);
  __bf16* VT = carve(4096ull * 256);
  __bf16* Ob = carve(4096ull * 1024);
  float* maskb = (float*)carve(8192);  // 4096 floats

  prep<<<6656, 256, 0, stream>>>(hidden, Wq, Wk, Wv, Wo, hb, Wqkvb, Wob);

  gemm_nt<true><<<dim3(32, 24), 256, 0, stream>>>(hb, Wqkvb, QKV, 1536);

  ropevt<<<11264, 256, 0, stream>>>(QKV, VT, amask, maskb);

  attn<<<dim3(8, 32, 2), 256, 0, stream>>>(QKV, VT, maskb, Ob);

  gemm_nt<false><<<dim3(32, 16), 256, 0, stream>>>(Ob, Wob, (void*)out, 1024);
}

// Round 9
// 183.831 us; speedup vs baseline: 1.1167x; 1.0864x over previous
//
#include <hip/hip_runtime.h>

typedef __bf16 bf16x8 __attribute__((ext_vector_type(8)));
typedef __bf16 bf16x4 __attribute__((ext_vector_type(4)));
typedef short short4v __attribute__((ext_vector_type(4)));
typedef float f32x4 __attribute__((ext_vector_type(4)));

__device__ __forceinline__ f32x4 mfma16(bf16x8 a, bf16x8 b, f32x4 c) {
  return __builtin_amdgcn_mfma_f32_16x16x32_bf16(a, b, c, 0, 0, 0);
}

// K=16 MFMA: C/D layout == B-operand layout -> S^T frags feed PV directly.
__device__ __forceinline__ f32x4 mfma16k16(bf16x4 a, bf16x4 b, f32x4 c) {
#if __has_builtin(__builtin_amdgcn_mfma_f32_16x16x16bf16_1k)
  short4v as = __builtin_bit_cast(short4v, a);
  short4v bs = __builtin_bit_cast(short4v, b);
  return __builtin_amdgcn_mfma_f32_16x16x16bf16_1k(as, bs, c, 0, 0, 0);
#else
  f32x4 d;
  asm volatile("v_mfma_f32_16x16x16_bf16 %0, %1, %2, %3"
               : "=v"(d)
               : "v"(a), "v"(b), "v"(c));
  return d;
#endif
}

__device__ __forceinline__ float fast_exp2(float x) {
  return __builtin_amdgcn_exp2f(x);  // v_exp_f32 (native exp2)
}

typedef const __attribute__((address_space(1))) void gvoid_t;
typedef __attribute__((address_space(3))) void svoid_t;
__device__ __forceinline__ void lds16(const __bf16* g, __bf16* l) {
  // async 16B/lane global->LDS; dest = wave-uniform base + lane*16
  __builtin_amdgcn_global_load_lds((gvoid_t*)g, (svoid_t*)l, 16, 0, 0);
}

// ---------------- fused fp32 -> bf16 convert of all inputs ----------------
__global__ __launch_bounds__(256) void prep(const float* __restrict__ hidden,
                                            const float* __restrict__ Wq,
                                            const float* __restrict__ Wk,
                                            const float* __restrict__ Wv,
                                            const float* __restrict__ Wo,
                                            __bf16* __restrict__ hb,
                                            __bf16* __restrict__ Wqkvb,
                                            __bf16* __restrict__ Wob) {
  int q = blockIdx.x * 256 + threadIdx.x;
  const float* src;
  __bf16* dst;
  if (q < 1048576) {
    src = hidden; dst = hb;
  } else if ((q -= 1048576) < 262144) {
    src = Wq; dst = Wqkvb;
  } else if ((q -= 262144) < 65536) {
    src = Wk; dst = Wqkvb + 1048576;
  } else if ((q -= 65536) < 65536) {
    src = Wv; dst = Wqkvb + 1310720;
  } else {
    q -= 65536;
    src = Wo; dst = Wob;
  }
  float4 v = *(const float4*)(src + (size_t)q * 4);
  bf16x4 o = { (__bf16)v.x, (__bf16)v.y, (__bf16)v.z, (__bf16)v.w };
  *(bf16x4*)(dst + (size_t)q * 4) = o;
}

// ------ NT GEMM, 128x128 tile, global_load_lds dbuf (R6 shape) ------
template <bool BF16_OUT>
__global__ __launch_bounds__(256) void gemm_nt(const __bf16* __restrict__ A,
                                               const __bf16* __restrict__ B,
                                               void* __restrict__ Cv, int N) {
  __shared__ __bf16 As[2][128][32];
  __shared__ __bf16 Bs[2][128][32];
  const int m0 = blockIdx.x * 128, n0 = blockIdx.y * 128;
  const int tid = threadIdx.x;
  const int wave = tid >> 6, lane = tid & 63, quad = lane >> 4, l16 = lane & 15;
  const int wr = wave >> 1, wc = wave & 1;
  const int srow = 32 * wave;  // wave stages rows srow..srow+31 (2 insts)
  const __bf16* Ag = A + (size_t)(m0 + srow + (lane >> 2)) * 1024 + (lane & 3) * 8;
  const __bf16* Bg = B + (size_t)(n0 + srow + (lane >> 2)) * 1024 + (lane & 3) * 8;
  f32x4 acc[4][4] = {};

  auto stage = [&](int buf, int k0) {
    lds16(Ag + k0, &As[buf][srow][0]);
    lds16(Ag + 16 * 1024 + k0, &As[buf][srow + 16][0]);
    lds16(Bg + k0, &Bs[buf][srow][0]);
    lds16(Bg + 16 * 1024 + k0, &Bs[buf][srow + 16][0]);
  };
  stage(0, 0);
  __syncthreads();
  int buf = 0;
  for (int k0 = 0; k0 < 1024; k0 += 32) {
    if (k0 + 32 < 1024) stage(buf ^ 1, k0 + 32);
    bf16x8 af[4], bfr[4];
#pragma unroll
    for (int i = 0; i < 4; i++)
      af[i] = *(bf16x8*)&As[buf][64 * wr + 16 * i + l16][quad * 8];
#pragma unroll
    for (int j = 0; j < 4; j++)
      bfr[j] = *(bf16x8*)&Bs[buf][64 * wc + 16 * j + l16][quad * 8];
#pragma unroll
    for (int i = 0; i < 4; i++)
#pragma unroll
      for (int j = 0; j < 4; j++) acc[i][j] = mfma16(af[i], bfr[j], acc[i][j]);
    __syncthreads();
    buf ^= 1;
  }
#pragma unroll
  for (int i = 0; i < 4; i++)
#pragma unroll
    for (int j = 0; j < 4; j++)
#pragma unroll
      for (int r = 0; r < 4; r++) {
        int row = m0 + 64 * wr + 16 * i + quad * 4 + r;
        int col = n0 + 64 * wc + 16 * j + l16;
        if constexpr (BF16_OUT)
          ((__bf16*)Cv)[(size_t)row * N + col] = (__bf16)acc[i][j][r];
        else
          ((float*)Cv)[(size_t)row * N + col] = acc[i][j][r];
      }
}

// --------- fused RoPE (in-place on QKV) + V transpose + mask bias ----------
__global__ __launch_bounds__(256) void ropevt(__bf16* __restrict__ QKV,
                                              __bf16* __restrict__ VT,
                                              const int* __restrict__ amask,
                                              float* __restrict__ maskb) {
  int idx = blockIdx.x * 256 + threadIdx.x;
  if (idx < 2621440) {
    __bf16* base;
    int m, i;
    if (idx < 2097152) {
      m = idx >> 9;
      int h = (idx >> 4) & 31;
      i = idx & 15;
      base = QKV + (size_t)m * 1536 + h * 32;
    } else {
      int j = idx - 2097152;
      m = j >> 7;
      int h = (j >> 4) & 7;
      i = j & 15;
      base = QKV + (size_t)m * 1536 + 1024 + h * 32;
    }
    int s = m & 2047;
    float inv = __expf(-(float)i * 0.5756462732485114f);  // 10000^(-i/16)
    float ang = (float)s * inv;
    float sn, cs;
    __sincosf(ang, &sn, &cs);
    float x0 = (float)base[i];
    float x1 = (float)base[i + 16];
    base[i] = (__bf16)(x0 * cs - x1 * sn);
    base[i + 16] = (__bf16)(x1 * cs + x0 * sn);
  } else {
    int j = idx - 2621440;
    if (j < 4096) maskb[j] = amask[j] ? -16.0f : -1.5e9f;  // static max folded in
    int s4 = j & 511;
    int d = (j >> 9) & 31;
    int hb_ = j >> 14;
    int s = s4 * 4;
    int b_ = hb_ >> 3, hkv_ = hb_ & 7;
    const __bf16* src = QKV + (size_t)(b_ * 2048 + s) * 1536 + 1280 + hkv_ * 32 + d;
    bf16x4 ov = { src[0], src[1536], src[3072], src[4608] };
    *(bf16x4*)&VT[((size_t)hb_ * 32 + d) * 2048 + s] = ov;
  }
}

// ------- Flash attention, split-K partials (static max => associative) ------
// Block (xp, z): for strips {xp, 15-xp}, z=0 handles the first half of each
// strip's key tiles, z=1 the second half -> uniform 17 tiles/block, 1024
// blocks (4/CU). Emits unnormalized f32 O-partial + rs-partial.
__global__ __launch_bounds__(256, 4) void attn(const __bf16* __restrict__ QKV,
                                               const __bf16* __restrict__ VT,
                                               const float* __restrict__ maskb,
                                               float* __restrict__ Opart,
                                               float* __restrict__ rspart) {
  __shared__ __bf16 Ks[2][64][40];
  __shared__ __bf16 Vs[2][32][72];
  const int tid = threadIdx.x;
  const int wave = tid >> 6, lane = tid & 63;
  const int quad = lane >> 4, l16 = lane & 15;
  const int b = blockIdx.z, h = blockIdx.y, hkv = h >> 2;
  const int xp = blockIdx.x >> 1, z = blockIdx.x & 1;
  const float SC2 = 0.25503472f;  // (1/sqrt(32)) * log2(e)

  const int sk_key = tid >> 2, sk_ch = (tid & 3) * 8;
  const int sv_d = tid >> 3, sv_seg = (tid & 7) * 8;
  const __bf16* ksrc = QKV + (size_t)(b * 2048 + sk_key) * 1536 + 1024 + hkv * 32 + sk_ch;
  const __bf16* vsrc = VT + ((size_t)(b * 8 + hkv) * 32 + sv_d) * 2048 + sv_seg;
  const float* mrow = maskb + b * 2048;

  for (int sp = 0; sp < 2; sp++) {
    const int strip = sp ? 15 - xp : xp;
    const int t_begin = z ? (strip + 1) : 0;
    const int t_end = z ? (2 * strip + 2) : (strip + 1);
    const int qw = strip * 128 + wave * 32;
    const int q_row0 = qw + l16, q_row1 = qw + 16 + l16;
    const __bf16* qbase = QKV + (size_t)(b * 2048 + qw + l16) * 1536 + h * 32 + quad * 8;
    bf16x8 qf0 = *(const bf16x8*)qbase;
    bf16x8 qf1 = *(const bf16x8*)(qbase + 16 * 1536);

    {  // stage tile t_begin into buffer 0
      uint4 kr = *(const uint4*)(ksrc + (size_t)t_begin * 64 * 1536);
      uint4 vr = *(const uint4*)(vsrc + (size_t)t_begin * 64);
      *(uint4*)&Ks[0][sk_key][sk_ch] = kr;
      *(uint4*)&Vs[0][sv_d][sv_seg] = vr;
    }
    __syncthreads();

    f32x4 o00 = {}, o01 = {}, o10 = {}, o11 = {};
    float rs0 = 0.f, rs1 = 0.f;
    int buf = 0;

    for (int t = t_begin; t < t_end; t++) {
      const int kv0 = t << 6;
      const bool more = (t + 1 < t_end);
      uint4 kr, vr;
      if (more) {
        kr = *(const uint4*)(ksrc + (size_t)(t + 1) * 64 * 1536);
        vr = *(const uint4*)(vsrc + (size_t)(t + 1) * 64);
      }
      if (kv0 <= qw + 31) {  // wave-uniform: any visible key?
        bf16x8 kf[4];
#pragma unroll
        for (int kt = 0; kt < 4; kt++)
          kf[kt] = *(bf16x8*)&Ks[buf][16 * kt + l16][quad * 8];
        f32x4 s0[4], s1[4];
#pragma unroll
        for (int kt = 0; kt < 4; kt++) {
          f32x4 zz = {};
          s0[kt] = mfma16(kf[kt], qf0, zz);
          s1[kt] = mfma16(kf[kt], qf1, zz);
        }
        // ---- static-max softmax -> packed B-operands (registers only) ----
        bf16x4 pb0[4], pb1[4];
        if (kv0 + 63 <= qw) {  // full tile
#pragma unroll
          for (int kt = 0; kt < 4; kt++) {
            const int kb = kv0 + 16 * kt + 4 * quad;
            float4 mb = *(const float4*)(mrow + kb);
#pragma unroll
            for (int r = 0; r < 4; r++) {
              float e0 = fast_exp2(fmaf(s0[kt][r], SC2, (&mb.x)[r]));
              float e1 = fast_exp2(fmaf(s1[kt][r], SC2, (&mb.x)[r]));
              rs0 += e0;
              rs1 += e1;
              pb0[kt][r] = (__bf16)e0;
              pb1[kt][r] = (__bf16)e1;
            }
          }
        } else {  // diagonal tile
#pragma unroll
          for (int kt = 0; kt < 4; kt++) {
            const int kb = kv0 + 16 * kt + 4 * quad;
            float4 mb = *(const float4*)(mrow + kb);
#pragma unroll
            for (int r = 0; r < 4; r++) {
              const int key = kb + r;
              float e0 = fast_exp2(fmaf(s0[kt][r], SC2, (&mb.x)[r]));
              float e1 = fast_exp2(fmaf(s1[kt][r], SC2, (&mb.x)[r]));
              e0 = (key <= q_row0) ? e0 : 0.f;
              e1 = (key <= q_row1) ? e1 : 0.f;
              rs0 += e0;
              rs1 += e1;
              pb0[kt][r] = (__bf16)e0;
              pb1[kt][r] = (__bf16)e1;
            }
          }
        }
        // ---- PV via K=16 MFMA: A = V^T frags (8B LDS reads), B = pb regs ---
#pragma unroll
        for (int kt = 0; kt < 4; kt++) {
          bf16x4 v0 = *(bf16x4*)&Vs[buf][l16][16 * kt + 4 * quad];
          bf16x4 v1 = *(bf16x4*)&Vs[buf][16 + l16][16 * kt + 4 * quad];
          o00 = mfma16k16(v0, pb0[kt], o00);
          o01 = mfma16k16(v1, pb0[kt], o01);
          o10 = mfma16k16(v0, pb1[kt], o10);
          o11 = mfma16k16(v1, pb1[kt], o11);
        }
      }
      if (more) {
        *(uint4*)&Ks[buf ^ 1][sk_key][sk_ch] = kr;
        *(uint4*)&Vs[buf ^ 1][sv_d][sv_seg] = vr;
      }
      __syncthreads();
      buf ^= 1;
    }
    // ---- partial epilogue: reduce rs, store unnormalized f32 O + rs ----
    rs0 += __shfl_xor(rs0, 16);
    rs0 += __shfl_xor(rs0, 32);
    rs1 += __shfl_xor(rs1, 16);
    rs1 += __shfl_xor(rs1, 32);
    float* Op = Opart + (size_t)z * 4096 * 1024;
    size_t row0 = (size_t)(b * 2048 + q_row0);
    size_t row1 = (size_t)(b * 2048 + q_row1);
    *(f32x4*)&Op[row0 * 1024 + h * 32 + quad * 4] = o00;
    *(f32x4*)&Op[row0 * 1024 + h * 32 + 16 + quad * 4] = o01;
    *(f32x4*)&Op[row1 * 1024 + h * 32 + quad * 4] = o10;
    *(f32x4*)&Op[row1 * 1024 + h * 32 + 16 + quad * 4] = o11;
    if (quad == 0) {
      size_t ri = ((size_t)(z * 2 + b) * 32 + h) * 2048;
      rspart[ri + q_row0] = rs0;
      rspart[ri + q_row1] = rs1;
    }
  }
}

// ---- combine partials: Ob = (O0 + O1) / (rs0 + rs1), bf16 ----
__global__ __launch_bounds__(256) void combine(const float* __restrict__ Opart,
                                               const float* __restrict__ rspart,
                                               __bf16* __restrict__ Ob) {
  int idx = blockIdx.x * 256 + threadIdx.x;  // 524288: (row, 8-elem group)
  int row = idx >> 7, g = idx & 127;
  int b = row >> 11, q = row & 2047, h = g >> 2;
  size_t off = (size_t)row * 1024 + g * 8;
  float4 a0 = *(const float4*)(Opart + off);
  float4 a1 = *(const float4*)(Opart + off + 4);
  float4 c0 = *(const float4*)(Opart + 4194304 + off);
  float4 c1 = *(const float4*)(Opart + 4194304 + off + 4);
  size_t ri = ((size_t)b * 32 + h) * 2048 + q;
  float inv = 1.0f / (rspart[ri] + rspart[2 * 65536 + ri]);
  bf16x8 w = { (__bf16)((a0.x + c0.x) * inv), (__bf16)((a0.y + c0.y) * inv),
               (__bf16)((a0.z + c0.z) * inv), (__bf16)((a0.w + c0.w) * inv),
               (__bf16)((a1.x + c1.x) * inv), (__bf16)((a1.y + c1.y) * inv),
               (__bf16)((a1.z + c1.z) * inv), (__bf16)((a1.w + c1.w) * inv) };
  *(bf16x8*)&Ob[off] = w;
}

extern "C" void kernel_launch(void* const* d_in, const int* in_sizes, int n_in,
                              void* d_out, int out_size, void* d_ws, size_t ws_size,
                              hipStream_t stream) {
  const float* hidden = (const float*)d_in[0];
  const int* amask = (const int*)d_in[1];
  const float* Wq = (const float*)d_in[2];
  const float* Wk = (const float*)d_in[3];
  const float* Wv = (const float*)d_in[4];
  const float* Wo = (const float*)d_in[5];
  float* out = (float*)d_out;

  char* p = (char*)d_ws;
  auto carve = [&](size_t elems) {
    __bf16* r = (__bf16*)p;
    p += ((elems * 2 + 255) / 256) * 256;
    return r;
  };
  __bf16* hb = carve(4096ull * 1024);
  __bf16* Wqkvb = carve(1536ull * 1024);
  __bf16* Wob = carve(1024ull * 1024);
  __bf16* QKV = carve(4096ull * 1536);
  __bf16* VT = carve(4096ull * 256);
  __bf16* Ob = carve(4096ull * 1024);
  float* maskb = (float*)carve(8192);                    // 4096 f32
  float* Opart = (float*)carve(2ull * 4096 * 1024 * 2);  // 2 x 16 MB f32
  float* rspart = (float*)carve(2ull * 2 * 32 * 2048 * 2);

  prep<<<6656, 256, 0, stream>>>(hidden, Wq, Wk, Wv, Wo, hb, Wqkvb, Wob);

  gemm_nt<true><<<dim3(32, 12), 256, 0, stream>>>(hb, Wqkvb, QKV, 1536);

  ropevt<<<11264, 256, 0, stream>>>(QKV, VT, amask, maskb);

  attn<<<dim3(16, 32, 2), 256, 0, stream>>>(QKV, VT, maskb, Opart, rspart);

  combine<<<2048, 256, 0, stream>>>(Opart, rspart, Ob);

  gemm_nt<false><<<dim3(32, 8), 256, 0, stream>>>(Ob, Wob, (void*)out, 1024);
}